// Round 4
// baseline (346.548 us; speedup 1.0000x reference)
//
#include <hip/hip_runtime.h>

typedef __attribute__((ext_vector_type(8))) short s16x8;
typedef __attribute__((ext_vector_type(4))) float f32x4;
typedef __attribute__((ext_vector_type(4))) int i32x4;
typedef __attribute__((ext_vector_type(2))) int i32x2;

#define HW2 262144  // 512*512
#define NSTATE 12

__device__ __forceinline__ unsigned f2b_bits(float f) {
  unsigned u = __builtin_bit_cast(unsigned, f);
  return (u + 0x7fffu + ((u >> 16) & 1u)) >> 16;  // RNE f32->bf16
}

__device__ __forceinline__ unsigned cvt_pk_bf16(float lo, float hi) {
  unsigned r;
  asm("v_cvt_pk_bf16_f32 %0, %1, %2" : "=v"(r) : "v"(lo), "v"(hi));
  return r;
}

// ---------------- prep: pack A1 (cw = w1@pw, 96x144 padded to 160), A2 (w2), cb ----------------
// A1 frag (kf 0..4, mf 0..5): lane l elem e holds cw[16mf + (l&15)][k], k = 32kf + 8(l>>4) + e;
//   k -> (sh = k>>4, s = k&15); zero for sh>=9 or s>=12.
// A2 frag f (0..2): lane l elem e holds w2[(l&15)][16(2f + (e>>2)) + 4(l>>4) + (e&3)], zero rows>=12.
__global__ void ca_prep(const float* __restrict__ pw, const float* __restrict__ pb,
                        const float* __restrict__ w1, const float* __restrict__ b1,
                        const float* __restrict__ w2,
                        short* __restrict__ A1, short* __restrict__ A2,
                        float* __restrict__ cb) {
  const int b = blockIdx.x, t = threadIdx.x;
  if (b < 30) {
    const int kf = b / 6, mf = b % 6;
    const int blk = t >> 4;
    const int row = 16 * mf + (t & 15);
    short v[8];
#pragma unroll
    for (int e = 0; e < 8; ++e) {
      const int k = 32 * kf + 8 * blk + e;
      const int sh = k >> 4, s = k & 15;
      float acc = 0.f;
      if (sh < 9 && s < 12) {
        const int ky = sh / 3, kx = sh % 3;
        for (int c = 0; c < 48; ++c)
          acc += w1[row * 48 + c] * pw[((c * 12 + s) * 3 + ky) * 3 + kx];
      }
      v[e] = (short)f2b_bits(acc);
    }
    short* dst = A1 + (b * 64 + t) * 8;
#pragma unroll
    for (int e = 0; e < 8; ++e) dst[e] = v[e];
  } else {
    const int blk = t >> 4, row = t & 15;
    for (int f = 0; f < 3; ++f) {
      short* dst = A2 + (f * 64 + t) * 8;
#pragma unroll
      for (int e = 0; e < 8; ++e) {
        const int k = 16 * (2 * f + (e >> 2)) + 4 * blk + (e & 3);
        const float val = (row < 12) ? w2[row * 96 + k] : 0.f;
        dst[e] = (short)f2b_bits(val);
      }
    }
    for (int j = t; j < 96; j += 64) {
      float a = b1[j];
      for (int c = 0; c < 48; ++c) a += w1[j * 48 + c] * pb[c];
      cb[j] = a;
    }
  }
}

// ---------------- main fused kernel ----------------
// 2 tiles per block (TY=8 x TX=64 each), double-buffered LDS, async stage split.
// LDS per buffer: channel-last bf16 [10][66][16] = 10560 shorts.
#define BUFS 10560

__launch_bounds__(256, 2)
__global__ void ca_main(const float* __restrict__ x, const int* __restrict__ mask,
                        const short* wsA1,  // NOT restrict: stores via `out` may alias ->
                                            // forbids remat of A1 loads -> frags stay resident
                        const short* __restrict__ wsA2,
                        const float* __restrict__ wscb, float* out /* NOT restrict */) {
  __shared__ short lds[2 * BUFS + 8 + 192];  // 2 tile bufs + 16B zero block + cb[96] f32
  const int ZOFF = 2 * BUFS;
  float* cbl = (float*)(lds + ZOFF + 8);

  const int tid = threadIdx.x;
  const int lane = tid & 63;
  const int blk = lane >> 4;
  const int col = lane & 15;
  const int wave = tid >> 6;

  const int gt0 = blockIdx.x * 2;          // even; pair never straddles an n boundary
  const int n = gt0 >> 9;
  const int base_n = n * NSTATE;
  const int rem0 = gt0 & 511, rem1 = rem0 + 1;
  const int y00 = (rem0 >> 3) * 8, x00 = (rem0 & 7) * 64;
  const int y01 = (rem1 >> 3) * 8, x01 = (rem1 & 7) * 64;

  // ---- per-thread weight fragments ----
  s16x8 A1[5][6];
#pragma unroll
  for (int kf = 0; kf < 5; ++kf)
#pragma unroll
    for (int mf = 0; mf < 6; ++mf)
      A1[kf][mf] = *(const s16x8*)(wsA1 + ((kf * 6 + mf) * 64 + lane) * 8);
  s16x8 A2[3];
#pragma unroll
  for (int f = 0; f < 3; ++f) A2[f] = *(const s16x8*)(wsA2 + (f * 64 + lane) * 8);

  // ---- staging state (registers) ----
  f32x4 rx[8];
  float hx = 0.f;

  auto stage_load = [&](int y0, int x0) {
#pragma unroll
    for (int i = 0; i < 8; ++i) {
      const int task = tid + (i << 8);
      if (task < 1920) {                       // task = ((ly*16 + q)*12 + s)
        const int rq = task / 12;
        const int s = task - rq * 12;
        const int q = rq & 15, ly = rq >> 4;
        const int gy = (y0 - 1 + ly) & 511;
        rx[i] = *(const f32x4*)(x + ((base_n + s) << 18) + (gy << 9) + x0 + (q << 2));
      }
    }
    if (tid < 240) {                           // halo columns lx=0,65
      const int r = tid >> 1, side = tid & 1;
      const int ly = r / 12;
      const int s = r - ly * 12;
      const int gy = (y0 - 1 + ly) & 511;
      const int gx = side ? ((x0 + 64) & 511) : ((x0 - 1) & 511);
      hx = x[((base_n + s) << 18) + (gy << 9) + gx];
    }
  };

  auto stage_write = [&](short* buf) {
#pragma unroll
    for (int i = 0; i < 8; ++i) {
      const int task = tid + (i << 8);
      if (task < 1920) {
        const int rq = task / 12;
        const int s = task - rq * 12;
        const int q = rq & 15, ly = rq >> 4;
        const int pix = ly * 66 + 1 + (q << 2);
        const unsigned w0 = cvt_pk_bf16(rx[i][0], rx[i][1]);
        const unsigned w1v = cvt_pk_bf16(rx[i][2], rx[i][3]);
        buf[(pix + 0) * 16 + s] = (short)w0;
        buf[(pix + 1) * 16 + s] = (short)(w0 >> 16);
        buf[(pix + 2) * 16 + s] = (short)w1v;
        buf[(pix + 3) * 16 + s] = (short)(w1v >> 16);
      }
    }
    if (tid < 240) {
      const int r = tid >> 1, side = tid & 1;
      const int ly = r / 12;
      const int s = r - ly * 12;
      buf[(ly * 66 + side * 65) * 16 + s] = (short)f2b_bits(hx);
    }
  };

  auto compute_tile = [&](const short* buf, int y0, int x0) {
    // epilogue prefetch for this wave's group 0
    f32x4 cxq = {0.f, 0.f, 0.f, 0.f};
    i32x4 cmq = {0, 0, 0, 0};
    auto ep_addr = [&](int gid) {
      return (base_n + col) * HW2 + ((y0 + (gid >> 2)) << 9) + x0 + ((gid & 3) << 4) + 4 * blk;
    };
    if (col < 12) {
      const int a = ep_addr(wave * 8);
      cxq = *(const f32x4*)(x + a);
      cmq = *(const i32x4*)(mask + a);
    }
#pragma unroll 1
    for (int i = 0; i < 8; ++i) {
      const int gid = wave * 8 + i;
      const int ty = gid >> 2;
      const int tx0 = (gid & 3) << 4;

      // B1 gather: 5 frags, one ds_read_b128 each (k = 32kf + 8blk + e)
      s16x8 b1f[5];
#pragma unroll
      for (int kf = 0; kf < 5; ++kf) {
        const int sh = 2 * kf + (blk >> 1);
        const short* ap;
        if (sh < 9) {
          const int ky = sh / 3, kx = sh - 3 * (sh / 3);
          ap = buf + ((ty + ky) * 66 + (tx0 + col + kx)) * 16 + 8 * (blk & 1);
        } else {
          ap = lds + ZOFF;
        }
        b1f[kf] = *(const s16x8*)ap;
      }

      // next group's epilogue prefetch (hides under MFMA block)
      f32x4 nxq = {0.f, 0.f, 0.f, 0.f};
      i32x4 nmq = {0, 0, 0, 0};
      if (col < 12) {
        const int a = ep_addr(wave * 8 + ((i + 1) & 7));
        nxq = *(const f32x4*)(x + a);
        nmq = *(const i32x4*)(mask + a);
      }

      // GEMM1: h = cw @ patch + cb (bias from LDS, broadcast reads)
      f32x4 hacc[6];
#pragma unroll
      for (int mf = 0; mf < 6; ++mf) hacc[mf] = *(const f32x4*)(cbl + 16 * mf + 4 * blk);
#pragma unroll
      for (int kf = 0; kf < 5; ++kf)
#pragma unroll
        for (int mf = 0; mf < 6; ++mf)
          hacc[mf] = __builtin_amdgcn_mfma_f32_16x16x32_bf16(A1[kf][mf], b1f[kf], hacc[mf], 0, 0, 0);

      // ReLU + cvt_pk pack, GEMM2 swapped: D2 rows = pixels, cols = states
      f32x4 upd = {0.f, 0.f, 0.f, 0.f};
#pragma unroll
      for (int f = 0; f < 3; ++f) {
        unsigned w[4];
#pragma unroll
        for (int j = 0; j < 4; ++j) {
          const float a = fmaxf(hacc[2 * f + (j >> 1)][2 * (j & 1)], 0.f);
          const float bb = fmaxf(hacc[2 * f + (j >> 1)][2 * (j & 1) + 1], 0.f);
          w[j] = cvt_pk_bf16(a, bb);
        }
        const i32x4 wv = {(int)w[0], (int)w[1], (int)w[2], (int)w[3]};
        const s16x8 b2f = __builtin_bit_cast(s16x8, wv);
        upd = __builtin_amdgcn_mfma_f32_16x16x32_bf16(b2f, A2[f], upd, 0, 0, 0);
      }

      // epilogue: lane owns state `col` (<12), 4 consecutive pixels
      if (col < 12) {
        const int a = ep_addr(gid);
        f32x4 o;
#pragma unroll
        for (int r = 0; r < 4; ++r) o[r] = cxq[r] + upd[r] * (float)cmq[r];
        *(f32x4*)(out + a) = o;
      }
      cxq = nxq;
      cmq = nmq;
    }
  };

  // ================== pipeline ==================
  stage_load(y00, x00);  // tile0 globals in flight

  // zero-init channels 12..15 of both buffers (stale-LDS NaN hazard) + zero block + cb
  for (int i = tid; i < 2 * 660; i += 256)
    *(i32x2*)(lds + i * 16 + 12) = (i32x2){0, 0};
  if (tid == 0) *(i32x4*)(lds + ZOFF) = (i32x4){0, 0, 0, 0};
  if (tid < 24) *(f32x4*)(cbl + tid * 4) = *(const f32x4*)(wscb + tid * 4);

  stage_write(lds);                 // waits tile0 loads, packs, writes buf0
  __syncthreads();

  stage_load(y01, x01);             // tile1 globals in flight across compute0
  compute_tile(lds, y00, x00);
  stage_write(lds + BUFS);
  __syncthreads();

  compute_tile(lds + BUFS, y01, x01);
}

extern "C" void kernel_launch(void* const* d_in, const int* in_sizes, int n_in,
                              void* d_out, int out_size, void* d_ws, size_t ws_size,
                              hipStream_t stream) {
  const float* x  = (const float*)d_in[0];
  const float* pw = (const float*)d_in[1];
  const float* pb = (const float*)d_in[2];
  const float* w1 = (const float*)d_in[3];
  const float* b1 = (const float*)d_in[4];
  const float* w2 = (const float*)d_in[5];
  const int* mask = (const int*)d_in[6];
  float* out = (float*)d_out;

  short* A1 = (short*)d_ws;                         // 30*64*16B = 30720
  short* A2 = (short*)((char*)d_ws + 30720);        // 3*64*16B  = 3072
  float* cb = (float*)((char*)d_ws + 30720 + 3072); // 96*4B

  ca_prep<<<31, 64, 0, stream>>>(pw, pb, w1, b1, w2, A1, A2, cb);
  ca_main<<<2048, 256, 0, stream>>>(x, mask, A1, A2, cb, out);
}

// Round 5
// 316.763 us; speedup vs baseline: 1.0940x; 1.0940x over previous
//
#include <hip/hip_runtime.h>

typedef __attribute__((ext_vector_type(8))) short s16x8;
typedef __attribute__((ext_vector_type(4))) float f32x4;
typedef __attribute__((ext_vector_type(4))) int i32x4;

#define HW2 262144  // 512*512
#define NSTATE 12

__device__ __forceinline__ unsigned f2b_bits(float f) {
  unsigned u = __builtin_bit_cast(unsigned, f);
  return (u + 0x7fffu + ((u >> 16) & 1u)) >> 16;  // RNE f32->bf16
}

__device__ __forceinline__ unsigned cvt_pk_bf16(float lo, float hi) {
  unsigned r;
  asm("v_cvt_pk_bf16_f32 %0, %1, %2" : "=v"(r) : "v"(lo), "v"(hi));
  return r;
}

// ---------------- prep: pack A1 (cw = w1@pw, 96x144 padded to 160), A2 (w2), cb ----------------
// A1 frag (kf 0..4, mf 0..5): lane l elem e holds cw[16mf + (l&15)][k], k = 32kf + 8(l>>4) + e;
//   k -> (sh = k>>4, s = k&15); zero for sh>=9 or s>=12.
// A2 frag f (0..2): lane l elem e holds w2[(l&15)][16(2f + (e>>2)) + 4(l>>4) + (e&3)], zero rows>=12.
__global__ void ca_prep(const float* __restrict__ pw, const float* __restrict__ pb,
                        const float* __restrict__ w1, const float* __restrict__ b1,
                        const float* __restrict__ w2,
                        short* __restrict__ A1, short* __restrict__ A2,
                        float* __restrict__ cb) {
  const int b = blockIdx.x, t = threadIdx.x;
  if (b < 30) {
    const int kf = b / 6, mf = b % 6;
    const int blk = t >> 4;
    const int row = 16 * mf + (t & 15);
    short v[8];
#pragma unroll
    for (int e = 0; e < 8; ++e) {
      const int k = 32 * kf + 8 * blk + e;
      const int sh = k >> 4, s = k & 15;
      float acc = 0.f;
      if (sh < 9 && s < 12) {
        const int ky = sh / 3, kx = sh % 3;
        for (int c = 0; c < 48; ++c)
          acc += w1[row * 48 + c] * pw[((c * 12 + s) * 3 + ky) * 3 + kx];
      }
      v[e] = (short)f2b_bits(acc);
    }
    short* dst = A1 + (b * 64 + t) * 8;
#pragma unroll
    for (int e = 0; e < 8; ++e) dst[e] = v[e];
  } else {
    const int blk = t >> 4, row = t & 15;
    for (int f = 0; f < 3; ++f) {
      short* dst = A2 + (f * 64 + t) * 8;
#pragma unroll
      for (int e = 0; e < 8; ++e) {
        const int k = 16 * (2 * f + (e >> 2)) + 4 * blk + (e & 3);
        const float val = (row < 12) ? w2[row * 96 + k] : 0.f;
        dst[e] = (short)f2b_bits(val);
      }
    }
    for (int j = t; j < 96; j += 64) {
      float a = b1[j];
      for (int c = 0; c < 48; ++c) a += w1[j * 48 + c] * pb[c];
      cb[j] = a;
    }
  }
}

// ---------------- main fused kernel ----------------
// Tile: TY=8 rows x TX=64 cols per block (4 waves). Round-3 skeleton + mask-in-LDS.
// LDS layout (shorts): [0,10560) x-tile [10][66][16] bf16 ch-last
//                      [10560,10568) zero block
//                      [10568,10760) cb (96 f32)
//                      [10760,13880) mask bytes [12][520]
#define ZOFF 10560
#define CBOFF 10568
#define MOFF 10760

// epilogue address for pixel-group gid: lane owns state `col`, pixels [.. +4) at 4*blk
#define EP_ADDR(gid) ((base_n + col) * HW2 + ((y0 + ((gid) >> 2)) << 9) + x0 + (((gid) & 3) << 4) + 4 * blk)

__launch_bounds__(256, 2)
__global__ void ca_main(const float* __restrict__ x, const int* __restrict__ mask,
                        const short* wsA1,  // NOT restrict: stores via `out` may alias ->
                                            // forbids remat of A1 loads -> frags stay resident
                        const short* __restrict__ wsA2,
                        const float* __restrict__ wscb, float* out /* NOT restrict */) {
  __shared__ short lds[13880];
  float* cbl = (float*)(lds + CBOFF);
  char* mlds = (char*)(lds + MOFF);

  const int tid = threadIdx.x;
  const int b = blockIdx.x;
  const int n = b >> 9;
  const int rem = b & 511;
  const int y0 = (rem >> 3) * 8;
  const int x0 = (rem & 7) * 64;

  const int lane = tid & 63;
  const int blk = lane >> 4;
  const int col = lane & 15;
  const int wave = tid >> 6;
  const int base_n = n * NSTATE;

  // ---- per-thread weight fragments ----
  s16x8 A1[5][6];
#pragma unroll
  for (int kf = 0; kf < 5; ++kf)
#pragma unroll
    for (int mf = 0; mf < 6; ++mf)
      A1[kf][mf] = *(const s16x8*)(wsA1 + ((kf * 6 + mf) * 64 + lane) * 8);
  s16x8 A2[3];
#pragma unroll
  for (int f = 0; f < 3; ++f) A2[f] = *(const s16x8*)(wsA2 + (f * 64 + lane) * 8);

  if (tid == 0) { *(i32x4*)(lds + ZOFF) = (i32x4){0, 0, 0, 0}; }
  if (tid < 24) *(f32x4*)(cbl + tid * 4) = *(const f32x4*)(wscb + tid * 4);

  // ---- stage mask (interior) into LDS as packed bytes [s][520] ----
  // 1536 tasks = 12 ch x 128 quads; task = s*128 + quad, consecutive tid -> consecutive quads.
#pragma unroll
  for (int i = 0; i < 6; ++i) {
    const int task = tid + (i << 8);
    const int s = task >> 7;
    const int quad = task & 127;
    const int pix = quad << 2;           // 4-aligned interior pixel index
    const int ly = pix >> 6, lx = pix & 63;
    const i32x4 mv = *(const i32x4*)(mask + ((base_n + s) << 18) + ((y0 + ly) << 9) + x0 + lx);
    const unsigned w = (unsigned)mv[0] | ((unsigned)mv[1] << 8) |
                       ((unsigned)mv[2] << 16) | ((unsigned)mv[3] << 24);
    *(unsigned*)(mlds + s * 520 + pix) = w;
  }

  // ---- stage x tile (with circular halo) into LDS as bf16, channel-last ----
  for (int p = tid; p < 660; p += 256) {
    const int ly = p / 66;
    const int lx = p - ly * 66;
    const int gy = (y0 - 1 + ly) & 511;
    const int gx = (x0 - 1 + lx) & 511;
    const int gbase = base_n * HW2 + (gy << 9) + gx;
    unsigned bs[12];
#pragma unroll
    for (int s = 0; s < 12; ++s) bs[s] = f2b_bits(x[gbase + s * HW2]);
    i32x4 v0 = {(int)(bs[0] | (bs[1] << 16)), (int)(bs[2] | (bs[3] << 16)),
                (int)(bs[4] | (bs[5] << 16)), (int)(bs[6] | (bs[7] << 16))};
    i32x4 v1 = {(int)(bs[8] | (bs[9] << 16)), (int)(bs[10] | (bs[11] << 16)), 0, 0};
    *(i32x4*)(lds + p * 16) = v0;
    *(i32x4*)(lds + p * 16 + 8) = v1;
  }
  __syncthreads();

  // ---- compute: each wave does 8 groups of 16 consecutive pixels ----
  // epilogue x prefetch for group 0 (L2-warm; mask comes from LDS)
  f32x4 cxq = {0.f, 0.f, 0.f, 0.f};
  if (col < 12) cxq = *(const f32x4*)(x + EP_ADDR(wave * 8));

#pragma unroll 1
  for (int i = 0; i < 8; ++i) {
    const int gid = wave * 8 + i;
    const int ty = gid >> 2;
    const int tx0 = (gid & 3) << 4;

    // B1 gather: 5 frags, one ds_read_b128 each (k = 32kf + 8blk + e)
    s16x8 b1f[5];
#pragma unroll
    for (int kf = 0; kf < 5; ++kf) {
      const int sh = 2 * kf + (blk >> 1);
      const short* ap;
      if (sh < 9) {
        const int ky = sh / 3, kx = sh - 3 * (sh / 3);
        ap = lds + ((ty + ky) * 66 + (tx0 + col + kx)) * 16 + 8 * (blk & 1);
      } else {
        ap = lds + ZOFF;
      }
      b1f[kf] = *(const s16x8*)ap;
    }

    // mask bits for this group from LDS (lane: state=col, 4 px at tx0+4blk)
    unsigned mword = 0;
    if (col < 12)
      mword = *(const unsigned*)(mlds + col * 520 + (ty << 6) + tx0 + (blk << 2));

    // next group's epilogue x prefetch (hides under MFMA block)
    f32x4 nxq = {0.f, 0.f, 0.f, 0.f};
    if (col < 12) nxq = *(const f32x4*)(x + EP_ADDR(wave * 8 + ((i + 1) & 7)));

    // GEMM1: h = cw @ patch + cb (bias from LDS broadcast)
    f32x4 hacc[6];
#pragma unroll
    for (int mf = 0; mf < 6; ++mf) hacc[mf] = *(const f32x4*)(cbl + 16 * mf + 4 * blk);
#pragma unroll
    for (int kf = 0; kf < 5; ++kf)
#pragma unroll
      for (int mf = 0; mf < 6; ++mf)
        hacc[mf] = __builtin_amdgcn_mfma_f32_16x16x32_bf16(A1[kf][mf], b1f[kf], hacc[mf], 0, 0, 0);

    // ReLU + cvt_pk pack, GEMM2 swapped: D2 rows = pixels, cols = states
    f32x4 upd = {0.f, 0.f, 0.f, 0.f};
#pragma unroll
    for (int f = 0; f < 3; ++f) {
      unsigned w[4];
#pragma unroll
      for (int j = 0; j < 4; ++j) {
        const float a = fmaxf(hacc[2 * f + (j >> 1)][2 * (j & 1)], 0.f);
        const float bb = fmaxf(hacc[2 * f + (j >> 1)][2 * (j & 1) + 1], 0.f);
        w[j] = cvt_pk_bf16(a, bb);
      }
      const i32x4 wv = {(int)w[0], (int)w[1], (int)w[2], (int)w[3]};
      const s16x8 b2f = __builtin_bit_cast(s16x8, wv);
      upd = __builtin_amdgcn_mfma_f32_16x16x32_bf16(b2f, A2[f], upd, 0, 0, 0);
    }

    // epilogue: lane owns state `col` (<12), 4 consecutive pixels
    if (col < 12) {
      const int a = EP_ADDR(gid);
      f32x4 o;
#pragma unroll
      for (int r = 0; r < 4; ++r)
        o[r] = cxq[r] + upd[r] * (float)((mword >> (8 * r)) & 1u);
      *(f32x4*)(out + a) = o;
    }
    cxq = nxq;
  }
}

extern "C" void kernel_launch(void* const* d_in, const int* in_sizes, int n_in,
                              void* d_out, int out_size, void* d_ws, size_t ws_size,
                              hipStream_t stream) {
  const float* x  = (const float*)d_in[0];
  const float* pw = (const float*)d_in[1];
  const float* pb = (const float*)d_in[2];
  const float* w1 = (const float*)d_in[3];
  const float* b1 = (const float*)d_in[4];
  const float* w2 = (const float*)d_in[5];
  const int* mask = (const int*)d_in[6];
  float* out = (float*)d_out;

  short* A1 = (short*)d_ws;                         // 30*64*16B = 30720
  short* A2 = (short*)((char*)d_ws + 30720);        // 3*64*16B  = 3072
  float* cb = (float*)((char*)d_ws + 30720 + 3072); // 96*4B

  ca_prep<<<31, 64, 0, stream>>>(pw, pb, w1, b1, w2, A1, A2, cb);
  ca_main<<<4096, 256, 0, stream>>>(x, mask, A1, A2, cb, out);
}